// Round 1
// baseline (10.248 us; speedup 1.0000x reference)
//
#include <hip/hip_runtime.h>
#include <utility>
#include <cstddef>

// ---------------------------------------------------------------------------
// Compile-time replication of the Python S2/S3 construction (MAX_L = 3).
// The sym tensors are pure functions of MAX_L, so the sparse pattern AND
// coefficients are baked in as constexpr; the kernel never reads S2/S3.
// ---------------------------------------------------------------------------
constexpr int MAXL = 3;
constexpr int NL   = 20;           // len(_l_list(3)) = 1+3+6+10
constexpr int NA2  = MAXL;         // 3
constexpr int NA3  = 13;           // number of S3 keys
constexpr int NOUT = 1 + NA2 + NA3;// 17
constexpr int C    = 16;           // channel dim

constexpr long long fact_(int n){ long long r=1; for(int i=2;i<=n;i++) r*=i; return r; }
constexpr float multinom_(int x,int y,int z){
    return (float)(fact_(x+y+z)/(fact_(x)*fact_(y)*fact_(z)));
}

// index of (x,y,z) in _l_list order
constexpr int lidx_(int x,int y,int z){
    int i=0;
    for(int L=0;L<=MAXL;L++)
      for(int lx=L;lx>=0;lx--)
        for(int ly=L-lx;ly>=0;ly--){
          int lz=L-lx-ly;
          if(lx==x&&ly==y&&lz==z) return i;
          i++;
        }
    return -1;
}

struct S3Pat {
    int n;
    int l1[400]; int l2[400]; int l3[400]; int a[400];
    float v[400];
};

constexpr S3Pat build_s3_(){
    S3Pat p{};
    int a=0;
    for(int m12=0;m12<=MAXL;m12++)
    for(int m13=0;m13<=MAXL-m12;m13++)
    for(int m23=0;m23<=MAXL;m23++){
        if(m12+m23>MAXL||m13+m23>MAXL) continue;
        if(m12+m13<1||m12+m23<1||m13+m23<1) continue;
        for(int ax=0;ax<=m12;ax++)for(int ay=0;ay<=m12-ax;ay++)
        for(int bx=0;bx<=m13;bx++)for(int by=0;by<=m13-bx;by++)
        for(int cx=0;cx<=m23;cx++)for(int cy=0;cy<=m23-cx;cy++){
            int az=m12-ax-ay, bz=m13-bx-by, cz=m23-cx-cy;
            int i1=lidx_(ax+bx,ay+by,az+bz);
            int i2=lidx_(ax+cx,ay+cy,az+cz);
            int i3=lidx_(bx+cx,by+cy,bz+cz);
            float pv=multinom_(ax,ay,az)*multinom_(bx,by,bz)*multinom_(cx,cy,cz);
            bool found=false;
            for(int t=0;t<p.n;t++){
                if(p.l1[t]==i1&&p.l2[t]==i2&&p.l3[t]==i3&&p.a[t]==a){
                    p.v[t]+=pv; found=true; break;
                }
            }
            if(!found){ p.l1[p.n]=i1;p.l2[p.n]=i2;p.l3[p.n]=i3;p.a[p.n]=a;p.v[p.n]=pv;p.n++; }
        }
        a++;
    }
    return p;
}
constexpr S3Pat S3P = build_s3_();

struct S2Pat { int n; int l[NL]; int a[NL]; float v[NL]; };
constexpr S2Pat build_s2_(){
    S2Pat p{};
    int i=0;
    for(int L=0;L<=MAXL;L++)
      for(int lx=L;lx>=0;lx--)
        for(int ly=L-lx;ly>=0;ly--){
            int lz=L-lx-ly;
            if(L>=1){ p.l[p.n]=i; p.a[p.n]=L-1; p.v[p.n]=multinom_(lx,ly,lz); p.n++; }
            i++;
        }
    return p;
}
constexpr S2Pat S2P = build_s2_();

// ---------------------------------------------------------------------------
// Fold-expression accumulators: indices are template parameters -> every
// array subscript is a frontend constant expression -> x[] / o[] stay in
// registers (no scratch), coefficients become immediates.
// ---------------------------------------------------------------------------
template<size_t... E>
__device__ __forceinline__ void s2_accum_(const float* x, float* o, std::index_sequence<E...>){
    ((o[1 + S2P.a[E]] = fmaf(S2P.v[E] * x[S2P.l[E]], x[S2P.l[E]], o[1 + S2P.a[E]])), ...);
}
template<size_t... E>
__device__ __forceinline__ void s3_accum_(const float* x, float* o, std::index_sequence<E...>){
    ((o[1 + NA2 + S3P.a[E]] =
        fmaf(S3P.v[E] * x[S3P.l1[E]], x[S3P.l2[E]] * x[S3P.l3[E]], o[1 + NA2 + S3P.a[E]])), ...);
}

__global__ __launch_bounds__(256) void sym_kernel(const float* __restrict__ na,
                                                  float* __restrict__ out,
                                                  int nfib){
    int t = blockIdx.x * blockDim.x + threadIdx.x;   // fiber index in [0, N*R*C)
    if (t >= nfib) return;
    int k = t & (C - 1);       // channel
    int q = t >> 4;            // combined (i*R + j)

    const float* base = na + (size_t)q * (NL * C) + k;
    float x[NL];
    #pragma unroll
    for (int l = 0; l < NL; ++l) x[l] = base[l * C];

    float o[NOUT];
    #pragma unroll
    for (int i = 0; i < NOUT; ++i) o[i] = 0.0f;
    o[0] = x[0];

    s2_accum_(x, o, std::make_index_sequence<S2P.n>{});
    s3_accum_(x, o, std::make_index_sequence<S3P.n>{});

    float* ob = out + (size_t)q * (NOUT * C) + k;
    #pragma unroll
    for (int a = 0; a < NOUT; ++a) ob[a * C] = o[a];
}

extern "C" void kernel_launch(void* const* d_in, const int* in_sizes, int n_in,
                              void* d_out, int out_size, void* d_ws, size_t ws_size,
                              hipStream_t stream) {
    const float* na = (const float*)d_in[0];
    float* out = (float*)d_out;
    int nfib = in_sizes[0] / NL;           // N*R*C = 131072
    int threads = 256;
    int blocks = (nfib + threads - 1) / threads;
    sym_kernel<<<blocks, threads, 0, stream>>>(na, out, nfib);
}